// Round 6
// baseline (127.208 us; speedup 1.0000x reference)
//
#include <hip/hip_runtime.h>

// Quantizer_189: 1-D VQ codebook lookup. x: [16,1,512,512] fp32 (N=4,194,304
// scalars; C=D=1 so transposes are no-ops), weight: [128,1].
//
// Reference model (NumPy fp32, per-op rounding, NO fma — verified rounds 3-5,
// absmax == 0.0):
//   dist_k = fl( fl( fl(x*x) + fl(w_k*w_k) ) - fl( fl(2x) * w_k ) )
//   idx    = np.argmin(dist) — first ORIGINAL index wins ties
//   out    = w[idx]
//
// Round-6: round 5 was latency-chain-bound (binary search = 3 dependent
// divergent LDS reads + 30-op cndmask tree; VALUBusy 40%, dur 52 us).
// Replace the search with a per-block direct-mapped cell table:
//   cell(x) = clamp((int)((x - lo) * invW), 0, G-1)   (monotone, pure VALU)
//   cnt[c]  = #{ sv[j] : cell(sv[j]) < c }  — EXACT pos bounds for any x in
//             cell c (cnt[c] <= pos(x) <= cnt[c+1]) because cell() is the
//             identical monotone fp function applied to the codebook.
//   record[c] = { sv[s..s+14], meta } with s = clamp(cnt[c]-4, 0, kk-15):
//             covers the +-4 noise margin around every bracket in the cell
//             when span = cnt[c+1]-cnt[c] <= 7 (else meta flags slow path).
// Records are 80 B (20 words) so consecutive records start on different
// banks; read as 4 aligned ds_read_b128. Hot path: cell hash + 4 gathers +
// 15 exact-fp32 evals. No dependent LDS chain.
//
// CRITICAL (round 1/2 lesson): device default -ffp-contract fuses mul into
// sub -> fma, breaking bit-exactness. Keep pragma + opaque asm barriers on
// every product.

constexpr int K     = 128;  // codebook capacity
constexpr int G     = 256;  // grid cells (== BLOCK: one cell per thread in setup)
constexpr int W     = 15;   // window values per record
constexpr int EPT   = 16;   // elements per thread (2 x float4-pair iterations)
constexpr int BLOCK = 256;

__device__ __forceinline__ int cellOf(float v, float lo, float invW) {
#pragma clang fp contract(off)
    float tf = (v - lo) * invW;     // fl(fl(v-lo)*invW), monotone in v
    int c = (int)tf;                // trunc toward zero — monotone over range
    c = c < 0 ? 0 : (c > G - 1 ? G - 1 : c);
    return c;
}

__global__ __launch_bounds__(BLOCK) void vq_kernel(const float* __restrict__ x,
                                                   const float* __restrict__ w,
                                                   float* __restrict__ out,
                                                   long n, int kk) {
#pragma clang fp contract(off)
    __shared__ float  wraw[K];      // original-order codebook (+inf padded)
    __shared__ float  sv[K];        // sorted values (+inf padded)
    __shared__ int    cnt[G + 1];   // cnt[c] = #{codebook entries in cells < c}
    __shared__ float4 tbl4[G * 5];  // 80 B/record: 15 window floats + meta + pad

    const int t = threadIdx.x;
    const float INF = __builtin_inff();

    if (t < K) {
        wraw[t] = (t < kk) ? w[t] : INF;
        sv[t]   = INF;
    }
    __syncthreads();
    if (t < kk) {
        // Stable O(K) rank sort (wraw[j] wave-uniform -> broadcast reads).
        float v = wraw[t];
        int rank = 0;
        for (int j = 0; j < kk; ++j) {
            float u = wraw[j];
            rank += (u < v) || (u == v && j < t);
        }
        sv[rank] = v;
    }
    __syncthreads();

    const float lo   = sv[0];
    const float hi   = sv[kk - 1];
    const float invW = (float)G / (hi - lo);   // same expression everywhere

    if (t < kk) {
        // Interval-write cnt[]: thread t owns cells (cell(sv[t-1]), cell(sv[t])].
        int cj = cellOf(sv[t], lo, invW);
        int cp = (t == 0) ? -1 : cellOf(sv[t - 1], lo, invW);
        for (int c = cp + 1; c <= cj; ++c) cnt[c] = t;
        if (t == kk - 1)
            for (int c = cj + 1; c <= G; ++c) cnt[c] = kk;
    }
    __syncthreads();

    {   // Build record for cell c == t (G == BLOCK).
        int cLo = cnt[t], cHi = cnt[t + 1];
        int maxS = kk - W; if (maxS < 0) maxS = 0;
        int s = cLo - 4; s = s < 0 ? 0 : (s > maxS ? maxS : s);
        int need = cHi + 3; int last = kk - 1; if (need > last) need = last;
        float meta = (need > s + W - 1) ? 1.0f : 0.0f;  // window insufficient
        float r[16];
#pragma unroll
        for (int i = 0; i < W; ++i) r[i] = sv[s + i];   // s+14 <= kk-1 < K
        r[15] = meta;
        float4* dst = &tbl4[t * 5];
        dst[0] = make_float4(r[0],  r[1],  r[2],  r[3]);
        dst[1] = make_float4(r[4],  r[5],  r[6],  r[7]);
        dst[2] = make_float4(r[8],  r[9],  r[10], r[11]);
        dst[3] = make_float4(r[12], r[13], r[14], r[15]);
    }
    __syncthreads();

    const long blockStart = (long)blockIdx.x * (BLOCK * EPT);
#pragma unroll
    for (int it = 0; it < EPT / 8; ++it) {
        long base = blockStart + (long)it * (BLOCK * 8) + (long)t * 8;
        if (base + 8 <= n) {
            float4 a = *(const float4*)(x + base);
            float4 b = *(const float4*)(x + base + 4);
            float xs[8] = {a.x, a.y, a.z, a.w, b.x, b.y, b.z, b.w};
            float res[8];
            int slowbits = 0;
#pragma unroll
            for (int e = 0; e < 8; ++e) {
                float xv = xs[e];
                float x2 = xv * xv;            // fl(x*x)
                asm volatile("" : "+v"(x2));   // block fma(x,x,·)
                float tx = xv + xv;            // fl(2x), exact

                int c = cellOf(xv, lo, invW);
                const float4* rec = &tbl4[c * 5];
                float4 r0 = rec[0], r1 = rec[1], r2 = rec[2], r3 = rec[3];
                float cand[W] = {r0.x, r0.y, r0.z, r0.w,
                                 r1.x, r1.y, r1.z, r1.w,
                                 r2.x, r2.y, r2.z, r2.w,
                                 r3.x, r3.y, r3.z};
                float meta = r3.w;

                float best = INF, bw = 0.0f;
                bool tie = false;
#pragma unroll
                for (int cc = 0; cc < W; ++cc) {
                    float wv = cand[cc];
                    float w2 = wv * wv;             // fl(w*w)
                    asm volatile("" : "+v"(w2));
                    float sum  = x2 + w2;           // fl(x^2 + w^2)
                    float prod = tx * wv;           // fl(2x * w)
                    asm volatile("" : "+v"(prod));  // block fma into sub
                    float d = sum - prod;           // fl(sum - prod)
                    bool lt = d < best;
                    bool eq = (!lt) && (d == best); // exact fp32-dist tie
                    tie  = lt ? false : (tie || eq);
                    best = lt ? d  : best;
                    bw   = lt ? wv : bw;
                }
                slowbits |= (tie || meta != 0.0f) ? (1 << e) : 0;
                res[e] = bw;
            }

            // Cold path: tie or flagged cell -> exact brute force, ORIGINAL
            // order (np.argmin first-index semantics by construction).
            if (__builtin_expect(__any(slowbits != 0), 0)) {
                for (int e = 0; e < 8; ++e) {
                    if (!(slowbits & (1 << e))) continue;
                    float xv = xs[e];
                    float x2 = xv * xv;
                    asm volatile("" : "+v"(x2));
                    float tx = xv + xv;
                    float best = INF, bwv = 0.0f;
                    for (int k2 = 0; k2 < kk; ++k2) {
                        float wv = wraw[k2];        // broadcast read
                        float w2 = wv * wv;
                        asm volatile("" : "+v"(w2));
                        float sum  = x2 + w2;
                        float prod = tx * wv;
                        asm volatile("" : "+v"(prod));
                        float d = sum - prod;
                        if (d < best) { best = d; bwv = wv; }  // first-min wins
                    }
                    res[e] = bwv;
                }
            }

            *(float4*)(out + base)     = make_float4(res[0], res[1], res[2], res[3]);
            *(float4*)(out + base + 4) = make_float4(res[4], res[5], res[6], res[7]);
        } else {
            // Tail (not hit for N=4,194,304): exact brute force per scalar.
            for (long i = base; i < n; ++i) {
                float xv = x[i];
                float x2 = xv * xv;
                asm volatile("" : "+v"(x2));
                float tx = xv + xv;
                float best = INF, bwv = 0.0f;
                for (int k2 = 0; k2 < kk; ++k2) {
                    float wv = wraw[k2];
                    float w2 = wv * wv;
                    asm volatile("" : "+v"(w2));
                    float sum  = x2 + w2;
                    float prod = tx * wv;
                    asm volatile("" : "+v"(prod));
                    float d = sum - prod;
                    if (d < best) { best = d; bwv = wv; }
                }
                out[i] = bwv;
            }
        }
    }
}

extern "C" void kernel_launch(void* const* d_in, const int* in_sizes, int n_in,
                              void* d_out, int out_size, void* d_ws, size_t ws_size,
                              hipStream_t stream) {
    const float* x = (const float*)d_in[0];
    const float* w = (const float*)d_in[1];
    float* out     = (float*)d_out;
    long n = (long)in_sizes[0];
    int  kk = in_sizes[1] < K ? in_sizes[1] : K;

    long perBlock = (long)BLOCK * EPT;
    long grid = (n + perBlock - 1) / perBlock;
    vq_kernel<<<(int)grid, BLOCK, 0, stream>>>(x, w, out, n, kk);
}

// Round 7
// 120.402 us; speedup vs baseline: 1.0565x; 1.0565x over previous
//
#include <hip/hip_runtime.h>

// Quantizer_189: 1-D VQ codebook lookup. x: [16,1,512,512] fp32 (N=4,194,304
// scalars; C=D=1 so transposes are no-ops), weight: [128,1].
//
// Reference model (NumPy fp32, per-op rounding, NO fma — verified rounds 3-6,
// absmax == 0.0):
//   dist_k = fl( fl( fl(x*x) + fl(w_k*w_k) ) - fl( fl(2x) * w_k ) )
//   idx    = np.argmin(dist) — first ORIGINAL index wins ties
//   out    = w[idx]
//
// Round-7 structure (fixes round 5/6 failures):
//  - cnt-bounds cell table: cellOf(x) is pure VALU; cntPak[c] packs
//    (cnt[c], cnt[c+1]) in one word -> ONE divergent LDS read, no dependent
//    binary-search chain. cnt[c] = #{entries with cell < c}; monotone cellOf
//    gives exact bounds cnt[c] <= pos(x) <= cnt[c+1].
//  - window reads from BANK-REPLICATED sorted array svrep[j*32 + lane%32]:
//    bank == lane%32 for any j -> conflict-free divergent reads (2 lanes/bank
//    is free). 16 KB.
//  - hot window W=10 starting at clamp(cnt[c]-4): covers pos in
//    [cnt[c], cnt[c]+2] with the verified +-4 noise margin (span<=2). Cells
//    with span>2 -> cold W=16 window (span<=8); span>8 or exact fp32-dist
//    tie -> cold brute force in ORIGINAL order (verified np.argmin handling).
//  - asm barriers are NON-volatile: still block fma contraction (the sub
//    consumes the asm result) but don't serialize — round 5's volatile asms
//    were totally ordered and killed ILP.
//  - EPT=8 -> 2048 blocks (8/CU grid headroom; round 6's EPT=16 grid-capped
//    occupancy at 50%).

constexpr int K     = 128;   // codebook capacity
constexpr int G     = 1024;  // cells
constexpr int EPT   = 8;     // elements per thread
constexpr int BLOCK = 256;
constexpr int W     = 10;    // hot window width  (covers span <= 2)
constexpr int WW    = 16;    // wide window width (covers span <= 8)

__device__ __forceinline__ int cellOf(float v, float lo, float invW) {
#pragma clang fp contract(off)
    float tf = (v - lo) * invW;   // monotone fp map (mul-of-sub: no fma form)
    int c = (int)tf;              // trunc: monotone, clamped below
    return c < 0 ? 0 : (c > G - 1 ? G - 1 : c);
}

__global__ __launch_bounds__(BLOCK) void vq_kernel(const float* __restrict__ x,
                                                   const float* __restrict__ w,
                                                   float* __restrict__ out,
                                                   long n, int kk) {
#pragma clang fp contract(off)
    __shared__ float    wraw[K];        // original-order codebook (+inf pad)
    __shared__ float    sv[K];          // sorted values (+inf pad)
    __shared__ float    svrep[K * 32];  // bank-replicated sorted values (16 KB)
    __shared__ unsigned cntPak[G];      // lo16=cnt[c], hi16=cnt[c+1] (4 KB)

    int* cntScratch = (int*)svrep;      // G+1 ints, used BEFORE svrep is filled

    const int t    = threadIdx.x;
    const int lane = t & 31;
    const float INF = __builtin_inff();

    if (t < K) { wraw[t] = (t < kk) ? w[t] : INF; sv[t] = INF; }
    __syncthreads();
    if (t < kk) {
        // Stable O(K) rank sort (broadcast reads).
        float v = wraw[t];
        int rank = 0;
        for (int j = 0; j < kk; ++j) {
            float u = wraw[j];
            rank += (u < v) || (u == v && j < t);
        }
        sv[rank] = v;
    }
    __syncthreads();
    const float lo   = sv[0];
    const float hi   = sv[kk - 1];
    const float invW = (hi > lo) ? ((float)G / (hi - lo)) : 0.0f;

    if (t < kk) {
        // cnt[c] = first sorted index with cell >= c, via interval writes.
        int cj = cellOf(sv[t], lo, invW);
        int cp = (t == 0) ? -1 : cellOf(sv[t - 1], lo, invW);
        for (int c = cp + 1; c <= cj; ++c) cntScratch[c] = t;
        if (t == kk - 1)
            for (int c = cj + 1; c <= G; ++c) cntScratch[c] = kk;
    }
    __syncthreads();
    for (int c = t; c < G; c += BLOCK)
        cntPak[c] = (unsigned)cntScratch[c] | ((unsigned)cntScratch[c + 1] << 16);
    __syncthreads();   // scratch consumed; svrep may now overwrite it
    for (int i = t; i < K * 32; i += BLOCK) svrep[i] = sv[i >> 5]; // linear, conflict-free
    __syncthreads();

    long base = ((long)blockIdx.x * BLOCK + t) * (long)EPT;
    if (kk >= WW && base + EPT <= n) {
        float4 a = *(const float4*)(x + base);
        float4 b = *(const float4*)(x + base + 4);
        float xs[EPT] = {a.x, a.y, a.z, a.w, b.x, b.y, b.z, b.w};
        float res[EPT];
        int wideBits = 0, bruteBits = 0;
#pragma unroll
        for (int e = 0; e < EPT; ++e) {
            float xv = xs[e];
            float x2 = xv * xv;  asm("" : "+v"(x2));   // fl(x*x), no fusion
            float tx = xv + xv;                        // fl(2x), exact

            int c = cellOf(xv, lo, invW);
            unsigned pk = cntPak[c];                   // one divergent b32
            int c0 = (int)(pk & 0xffffu);
            int c1 = (int)(pk >> 16);
            int s  = c0 - 4;
            int smax = kk - W;
            s = s < 0 ? 0 : (s > smax ? smax : s);

            int wb = (s << 5) | lane;                  // svrep base index
            float best = INF, bw = 0.0f;
            bool tie = false;
#pragma unroll
            for (int cc = 0; cc < W; ++cc) {
                float wv = svrep[wb + (cc << 5)];      // conflict-free b32
                float w2 = wv * wv;  asm("" : "+v"(w2));   // fl(w*w)
                float sum  = x2 + w2;                      // fl(x^2+w^2)
                float prod = tx * wv; asm("" : "+v"(prod));// fl(2x*w)
                float d = sum - prod;                      // fl(sum-prod)
                bool lt = d < best;
                bool eq = (!lt) && (d == best);
                tie  = lt ? false : (tie || eq);
                best = lt ? d  : best;
                bw   = lt ? wv : bw;
            }
            res[e] = bw;
            wideBits  |= (c1 - c0 > W - 8) ? (1 << e) : 0;  // span > 2
            bruteBits |= tie ? (1 << e) : 0;
        }

        // Cold: span>2 cells — wide window (covers span<=8).
        if (__builtin_expect(__any(wideBits != 0), 0)) {
            for (int e = 0; e < EPT; ++e) {
                if (!(wideBits & (1 << e))) continue;
                float xv = xs[e];
                float x2 = xv * xv;  asm("" : "+v"(x2));
                float tx = xv + xv;
                int c = cellOf(xv, lo, invW);
                unsigned pk = cntPak[c];
                int c0 = (int)(pk & 0xffffu);
                int c1 = (int)(pk >> 16);
                int s  = c0 - 4;
                int smax = kk - WW;
                s = s < 0 ? 0 : (s > smax ? smax : s);
                float best = INF, bw = 0.0f;
                bool tie = false;
                for (int cc = 0; cc < WW; ++cc) {
                    float wv = svrep[((s + cc) << 5) | lane];
                    float w2 = wv * wv;  asm("" : "+v"(w2));
                    float sum  = x2 + w2;
                    float prod = tx * wv; asm("" : "+v"(prod));
                    float d = sum - prod;
                    bool lt = d < best;
                    bool eq = (!lt) && (d == best);
                    tie  = lt ? false : (tie || eq);
                    best = lt ? d  : best;
                    bw   = lt ? wv : bw;
                }
                res[e] = bw;
                if (tie || (c1 - c0 > WW - 8)) bruteBits |= (1 << e);
            }
        }

        // Cold^2: tie or span>8 — exact brute force, ORIGINAL order
        // (np.argmin first-index by strict <). Verified rounds 3-6.
        if (__builtin_expect(__any(bruteBits != 0), 0)) {
            for (int e = 0; e < EPT; ++e) {
                if (!(bruteBits & (1 << e))) continue;
                float xv = xs[e];
                float x2 = xv * xv;  asm("" : "+v"(x2));
                float tx = xv + xv;
                float best = INF, bwv = 0.0f;
                for (int k2 = 0; k2 < kk; ++k2) {
                    float wv = wraw[k2];               // broadcast
                    float w2 = wv * wv;  asm("" : "+v"(w2));
                    float sum  = x2 + w2;
                    float prod = tx * wv; asm("" : "+v"(prod));
                    float d = sum - prod;
                    if (d < best) { best = d; bwv = wv; }
                }
                res[e] = bwv;
            }
        }

        *(float4*)(out + base)     = make_float4(res[0], res[1], res[2], res[3]);
        *(float4*)(out + base + 4) = make_float4(res[4], res[5], res[6], res[7]);
    } else {
        // Tail / tiny-codebook fallback: exact brute force per scalar.
        long end = base + EPT; if (end > n) end = n;
        for (long i = base; i < end; ++i) {
            float xv = x[i];
            float x2 = xv * xv;  asm("" : "+v"(x2));
            float tx = xv + xv;
            float best = INF, bwv = 0.0f;
            for (int k2 = 0; k2 < kk; ++k2) {
                float wv = wraw[k2];
                float w2 = wv * wv;  asm("" : "+v"(w2));
                float sum  = x2 + w2;
                float prod = tx * wv; asm("" : "+v"(prod));
                float d = sum - prod;
                if (d < best) { best = d; bwv = wv; }
            }
            out[i] = bwv;
        }
    }
}

extern "C" void kernel_launch(void* const* d_in, const int* in_sizes, int n_in,
                              void* d_out, int out_size, void* d_ws, size_t ws_size,
                              hipStream_t stream) {
    const float* x = (const float*)d_in[0];
    const float* w = (const float*)d_in[1];
    float* out     = (float*)d_out;
    long n = (long)in_sizes[0];
    int  kk = in_sizes[1] < K ? in_sizes[1] : K;

    long perBlock = (long)BLOCK * EPT;
    long grid = (n + perBlock - 1) / perBlock;
    vq_kernel<<<(int)grid, BLOCK, 0, stream>>>(x, w, out, n, kk);
}

// Round 8
// 117.257 us; speedup vs baseline: 1.0849x; 1.0268x over previous
//
#include <hip/hip_runtime.h>

// Quantizer_189: 1-D VQ codebook lookup. x: [16,1,512,512] fp32 (N=4,194,304
// scalars; C=D=1 so transposes are no-ops), weight: [128,1].
//
// Reference model (NumPy fp32, per-op rounding, NO fma — verified rounds 3-7,
// absmax == 0.0):
//   dist_k = fl( fl( fl(x*x) + fl(w_k*w_k) ) - fl( fl(2x) * w_k ) )
//   idx    = np.argmin(dist) — first ORIGINAL index wins ties
//   out    = w[idx]
//
// Round-8: round 7's counters showed per-block setup (sort + cnt build +
// 16KB replication, x2048 blocks) cost as much as the hot loop. Split:
//   Kernel A (1 block): sort codebook, build cell table, write to d_ws:
//     hdr {lo, invW, kk, mode} | svrep[K*32] bank-replicated | spak[G].
//     spak[c] = s | c0<<8 | c1<<16 | wide<<31, s = clamp(c0-4, 0, kk-W).
//   Kernel B (2048 blocks): stage 20.5KB via 5 linear float4 copies/thread,
//     then: cell hash -> 1 spak read -> 10 conflict-free svrep reads ->
//     10 exact-fp32 evals. Cold: span>2 -> W=16 window; span>8 or exact
//     fp32-dist tie -> brute force in ORIGINAL order reading global w.
//
// CRITICAL (round 1/2 lesson): device default -ffp-contract fuses mul into
// sub -> fma, breaking bit-exactness. Keep pragma + NON-volatile asm
// barriers on every product (volatile asms serialize — round 5 lesson).

constexpr int K     = 128;   // codebook capacity
constexpr int G     = 1024;  // cells
constexpr int EPT   = 8;     // elements per thread
constexpr int BLOCK = 256;
constexpr int W     = 10;    // hot window width  (covers span <= 2)
constexpr int WW    = 16;    // wide window width (covers span <= 8)

// d_ws layout (32-bit words):
//   [0] lo  [1] invW  [2] kk  [3] mode    (16 B header)
//   [4 .. 4+K*32)            svrep        (16 KB, 16B-aligned)
//   [4+K*32 .. 4+K*32+G)     spak         (4 KB, 16B-aligned)
constexpr int WS_WORDS = 4 + K * 32 + G;

__device__ __forceinline__ int cellOf(float v, float lo, float invW) {
#pragma clang fp contract(off)
    float tf = (v - lo) * invW;   // monotone fp map
    int c = (int)tf;
    return c < 0 ? 0 : (c > G - 1 ? G - 1 : c);
}

__global__ __launch_bounds__(BLOCK) void setup_kernel(const float* __restrict__ w,
                                                      float* __restrict__ ws,
                                                      int kk) {
#pragma clang fp contract(off)
    __shared__ float sv[K];
    __shared__ int   cnt[G + 1];
    const int t = threadIdx.x;
    const float INF = __builtin_inff();

    if (t < K) sv[t] = INF;
    __syncthreads();
    if (t < kk) {
        // Stable O(K) rank sort (w[j] uniform -> scalar/broadcast loads).
        float v = w[t];
        int rank = 0;
        for (int j = 0; j < kk; ++j) {
            float u = w[j];
            rank += (u < v) || (u == v && j < t);
        }
        sv[rank] = v;
    }
    __syncthreads();

    const float lo   = sv[0];
    const float hi   = sv[kk - 1];
    const float invW = (hi > lo) ? ((float)G / (hi - lo)) : 0.0f;

    if (t < kk) {
        // cnt[c] = #{entries with cell < c}, via interval writes.
        int cj = cellOf(sv[t], lo, invW);
        int cp = (t == 0) ? -1 : cellOf(sv[t - 1], lo, invW);
        for (int c = cp + 1; c <= cj; ++c) cnt[c] = t;
        if (t == kk - 1)
            for (int c = cj + 1; c <= G; ++c) cnt[c] = kk;
    }
    __syncthreads();

    if (t == 0) {
        ws[0] = lo;
        ws[1] = invW;
        ((int*)ws)[2] = kk;
        ((int*)ws)[3] = (kk >= WW) ? 0 : 1;   // mode 1: brute everything
    }
    for (int i = t; i < K * 32; i += BLOCK)   // bank-replicated sorted values
        ws[4 + i] = sv[i >> 5];
    unsigned* spak = (unsigned*)(ws + 4 + K * 32);
    int smaxH = kk - W;  if (smaxH < 0) smaxH = 0;
    for (int c = t; c < G; c += BLOCK) {
        int c0 = cnt[c], c1 = cnt[c + 1];
        int s = c0 - 4;  s = s < 0 ? 0 : (s > smaxH ? smaxH : s);
        unsigned wide = (c1 - c0 > 2) ? 0x80000000u : 0u;
        spak[c] = (unsigned)s | ((unsigned)c0 << 8) | ((unsigned)c1 << 16) | wide;
    }
}

__device__ __forceinline__ float bruteOne(float xv, const float* __restrict__ w,
                                          int kk) {
#pragma clang fp contract(off)
    // Exact brute force in ORIGINAL order (np.argmin first-index via strict <).
    float x2 = xv * xv;  asm("" : "+v"(x2));
    float tx = xv + xv;
    float best = __builtin_inff(), bwv = 0.0f;
    for (int k = 0; k < kk; ++k) {
        float wv = w[k];                       // uniform -> broadcast, L2-hot
        float w2 = wv * wv;  asm("" : "+v"(w2));
        float sum  = x2 + w2;
        float prod = tx * wv; asm("" : "+v"(prod));
        float d = sum - prod;
        if (d < best) { best = d; bwv = wv; }
    }
    return bwv;
}

__global__ __launch_bounds__(BLOCK) void vq_kernel(const float* __restrict__ x,
                                                   const float* __restrict__ w,
                                                   float* __restrict__ out,
                                                   const float* __restrict__ ws,
                                                   long n) {
#pragma clang fp contract(off)
    __shared__ float    svrep[K * 32];  // 16 KB bank-replicated sorted values
    __shared__ unsigned spak[G];        // 4 KB packed cell records

    const int t    = threadIdx.x;
    const int lane = t & 31;
    const float INF = __builtin_inff();

    // Stage tables: 5 linear float4 copies per thread.
    {
        const float4* g4 = (const float4*)(ws + 4);
        float4* l4 = (float4*)svrep;
#pragma unroll
        for (int i = 0; i < 4; ++i) l4[t + i * BLOCK] = g4[t + i * BLOCK];
        const float4* s4 = (const float4*)(ws + 4 + K * 32);
        ((float4*)spak)[t] = s4[t];
    }
    const float lo   = ws[0];
    const float invW = ws[1];
    const int   kk   = ((const int*)ws)[2];
    const int   mode = ((const int*)ws)[3];
    __syncthreads();

    long base = ((long)blockIdx.x * BLOCK + t) * (long)EPT;
    if (mode == 0 && base + EPT <= n) {
        float4 a = *(const float4*)(x + base);
        float4 b = *(const float4*)(x + base + 4);
        float xs[EPT] = {a.x, a.y, a.z, a.w, b.x, b.y, b.z, b.w};
        float res[EPT];
        int slowBits = 0;
#pragma unroll
        for (int e = 0; e < EPT; ++e) {
            float xv = xs[e];
            float x2 = xv * xv;  asm("" : "+v"(x2));   // fl(x*x), no fusion
            float tx = xv + xv;                        // fl(2x), exact

            int c = cellOf(xv, lo, invW);
            unsigned pk = spak[c];                     // one divergent b32
            int s = (int)(pk & 0xffu);
            int wb = (s << 5) | lane;                  // svrep base index

            float best = INF, bw = 0.0f;
            bool tie = false;
#pragma unroll
            for (int cc = 0; cc < W; ++cc) {
                float wv = svrep[wb + (cc << 5)];      // conflict-free b32
                float w2 = wv * wv;  asm("" : "+v"(w2));    // fl(w*w)
                float sum  = x2 + w2;                       // fl(x^2+w^2)
                float prod = tx * wv; asm("" : "+v"(prod)); // fl(2x*w)
                float d = sum - prod;                       // fl(sum-prod)
                bool lt = d < best;
                bool eq = (!lt) && (d == best);
                tie  = lt ? false : (tie || eq);
                best = lt ? d  : best;
                bw   = lt ? wv : bw;
            }
            res[e] = bw;
            slowBits |= (tie || (int)pk < 0) ? (1 << e) : 0;  // tie or wide cell
        }

        // Cold: wide window (span<=8) or escalate to brute.
        if (__builtin_expect(__any(slowBits != 0), 0)) {
            int smaxW = kk - WW;  if (smaxW < 0) smaxW = 0;
            for (int e = 0; e < EPT; ++e) {
                if (!(slowBits & (1 << e))) continue;
                float xv = xs[e];
                float x2 = xv * xv;  asm("" : "+v"(x2));
                float tx = xv + xv;
                int c = cellOf(xv, lo, invW);
                unsigned pk = spak[c];
                int c0 = (int)((pk >> 8)  & 0xffu);
                int c1 = (int)((pk >> 16) & 0xffu);
                int s  = c0 - 4;  s = s < 0 ? 0 : (s > smaxW ? smaxW : s);
                float best = INF, bw = 0.0f;
                bool tie = false;
                for (int cc = 0; cc < WW; ++cc) {
                    float wv = svrep[((s + cc) << 5) | lane];
                    float w2 = wv * wv;  asm("" : "+v"(w2));
                    float sum  = x2 + w2;
                    float prod = tx * wv; asm("" : "+v"(prod));
                    float d = sum - prod;
                    bool lt = d < best;
                    bool eq = (!lt) && (d == best);
                    tie  = lt ? false : (tie || eq);
                    best = lt ? d  : best;
                    bw   = lt ? wv : bw;
                }
                res[e] = (tie || (c1 - c0 > WW - 8)) ? bruteOne(xv, w, kk) : bw;
            }
        }

        *(float4*)(out + base)     = make_float4(res[0], res[1], res[2], res[3]);
        *(float4*)(out + base + 4) = make_float4(res[4], res[5], res[6], res[7]);
    } else {
        // Tail or tiny-codebook mode: exact brute force per scalar.
        long end = base + EPT; if (end > n) end = n;
        for (long i = base; i < end; ++i) out[i] = bruteOne(x[i], w, kk);
    }
}

// Fallback if d_ws is too small for the tables (not expected): plain brute.
__global__ __launch_bounds__(BLOCK) void vq_brute(const float* __restrict__ x,
                                                  const float* __restrict__ w,
                                                  float* __restrict__ out,
                                                  long n, int kk) {
#pragma clang fp contract(off)
    long base = ((long)blockIdx.x * BLOCK + threadIdx.x) * (long)EPT;
    long end = base + EPT; if (end > n) end = n;
    for (long i = base; i < end; ++i) out[i] = bruteOne(x[i], w, kk);
}

extern "C" void kernel_launch(void* const* d_in, const int* in_sizes, int n_in,
                              void* d_out, int out_size, void* d_ws, size_t ws_size,
                              hipStream_t stream) {
    const float* x = (const float*)d_in[0];
    const float* w = (const float*)d_in[1];
    float* out     = (float*)d_out;
    long n  = (long)in_sizes[0];
    int  kk = in_sizes[1] < K ? in_sizes[1] : K;

    long perBlock = (long)BLOCK * EPT;
    long grid = (n + perBlock - 1) / perBlock;

    if (ws_size < sizeof(float) * WS_WORDS) {
        vq_brute<<<(int)grid, BLOCK, 0, stream>>>(x, w, out, n, kk);
        return;
    }
    float* ws = (float*)d_ws;
    setup_kernel<<<1, BLOCK, 0, stream>>>(w, ws, kk);
    vq_kernel<<<(int)grid, BLOCK, 0, stream>>>(x, w, out, ws, n);
}